// Round 18
// baseline (2950.563 us; speedup 1.0000x reference)
//
#include <hip/hip_runtime.h>
#include <hip/hip_bf16.h>

typedef unsigned int u32;
typedef unsigned short u16;
typedef u32 u32x4 __attribute__((ext_vector_type(4)));
typedef _Float16 h16x2 __attribute__((ext_vector_type(2)));

// ---------------------------------------------------------------------------
// B=32, N=64, R=256. 32 WGs x 512 threads, 1 batch/WG.
// Thread: col = w8*32 + (l&31), K-half g = l>>5 (in-wave K-split).
//
// ROUND-17 BASE (1.93ms, absmax 0.0156): descriptor loop, fdot2 f16,
// out-fold (A=O1+Q1@O3, B=Q3@O3, poO=po+pq@O3), 21 items/step.
// ROUND-18 CHANGES:
//  (1) odd-stride LDS rows (SREPT 37 u32, SKEY 133 u32, swizzle dropped):
//      stride mod 32 = 5 (coprime) -> bank-optimal; kills the 4-way
//      conflicts behind SQ_LDS_BANK_CONFLICT=1.49e7.
//  (2) 3-buffer quarter pipeline: both quarters of item n+1 issued during
//      item n (~256cyc lookahead vs L2 ~300cyc), static A/B/C rotation
//      (21 % 3 == 0 -> rotation invariant across steps). VGPR 64->~96.
//
// Panel u16 layout: e = pid*65536 + w8*8192 + c*4096 + r*512 + l*8 + j
//   -> col = w8*32+(l&31), K = (2*(l>>5)+c)*64 + r*8 + j.
// ---------------------------------------------------------------------------

struct G4 { const float* Bm[4]; const float* bias[4]; float* C[4]; };

__global__ __launch_bounds__(256) void gemm16(const float* __restrict__ A, G4 g) {
  __shared__ float At[16 * 256];
  const int sub = blockIdx.y;
  const float* __restrict__ Bm = g.Bm[sub];
  const float* __restrict__ bias = g.bias[sub];
  float* __restrict__ C = g.C[sub];
  const int r0 = blockIdx.x * 16;
  const int t = threadIdx.x;
#pragma unroll
  for (int j = 0; j < 16; ++j) At[j * 256 + t] = A[(r0 + j) * 256 + t];
  __syncthreads();
  float acc[16];
#pragma unroll
  for (int j = 0; j < 16; ++j) acc[j] = 0.f;
  for (int k = 0; k < 256; ++k) {
    const float bv = Bm[k * 256 + t];
#pragma unroll
    for (int j = 0; j < 16; ++j) acc[j] = fmaf(At[j * 256 + k], bv, acc[j]);
  }
  const float bs = bias[t];
#pragma unroll
  for (int j = 0; j < 16; ++j) C[(r0 + j) * 256 + t] = acc[j] + bs;
}

// C = A@B (+D); rows = gridDim.x*16
__global__ __launch_bounds__(256) void gemmD(const float* __restrict__ A,
                                             const float* __restrict__ B,
                                             const float* __restrict__ D,
                                             float* __restrict__ C) {
  __shared__ float At[16 * 256];
  const int r0 = blockIdx.x * 16;
  const int t = threadIdx.x;
#pragma unroll
  for (int j = 0; j < 16; ++j) At[j * 256 + t] = A[(r0 + j) * 256 + t];
  __syncthreads();
  float acc[16];
#pragma unroll
  for (int j = 0; j < 16; ++j) acc[j] = 0.f;
  for (int k = 0; k < 256; ++k) {
    const float bv = B[k * 256 + t];
#pragma unroll
    for (int j = 0; j < 16; ++j) acc[j] = fmaf(At[j * 256 + k], bv, acc[j]);
  }
#pragma unroll
  for (int j = 0; j < 16; ++j) {
    const float dv = D ? D[(r0 + j) * 256 + t] : 0.f;
    C[(r0 + j) * 256 + t] = acc[j] + dv;
  }
}

struct C12 { const float* src[12]; };

__device__ __forceinline__ u16 f16b(float x) {
  union { _Float16 h; u16 u; } c; c.h = (_Float16)x; return c.u;
}
__device__ __forceinline__ u32 pk2f(float a, float b) {
  return (u32)f16b(a) | ((u32)f16b(b) << 16);
}
__device__ __forceinline__ float f16f(u16 x) {
  union { u16 u; _Float16 h; } c; c.u = x; return (float)c.h;
}
__device__ __forceinline__ h16x2 ash2(u32 x) {
  union { u32 u; h16x2 h; } c; c.u = x; return c.h;
}

#if __has_builtin(__builtin_amdgcn_fdot2)
#define FDOT2(A, W, X) A = __builtin_amdgcn_fdot2(ash2(W), ash2(X), A, false)
#else
#define FDOT2(A, W, X) \
  asm("v_dot2_f32_f16 %0, %1, %2, %0" : "+v"(A) : "v"(W), "v"(X))
#endif

__global__ __launch_bounds__(256) void cvt_panels(C12 c, u16* __restrict__ dst) {
  const int z = blockIdx.y;
  const float* __restrict__ in = c.src[z];
  const int e = blockIdx.x * 256 + threadIdx.x;   // [0, 65536)
  const int j = e & 7, l = (e >> 3) & 63, r = (e >> 9) & 7;
  const int cc = (e >> 12) & 1, w8 = e >> 13;
  const int col = w8 * 32 + (l & 31);
  const int k = (2 * (l >> 5) + cc) * 64 + r * 8 + j;
  dst[z * 65536 + e] = f16b(in[k * 256 + col]);
}

// ---------------- main kernel --------------------------------------------
#define PID_F1 0

// LDS offsets (u32 units); row strides 37 / 133 (mod 32 = 5, coprime)
#define OFF_SREPT 0       // [256 cols][37] u32 (64 nodes f16 + pad)
#define OFF_SKEY  9472    // [64 nodes][133] u32 (256 k f16 + pad)
#define OFF_ATTW  17984   // [8 waves][32] u32 (64 nodes f16)
#define OFF_XQR   18240   // [128] u32 (256 cols f16)
#define OFF_XFH   18368
#define OFF_XO    18496
#define OFF_H2    18624   // [2][128]
#define OFF_Q2    18880   // [2][128]
#define LDS_U32   19136   // 76,544 B

#define BAR() asm volatile("s_waitcnt lgkmcnt(0)\n\ts_barrier" ::: "memory")
#define SB()  __builtin_amdgcn_sched_barrier(0)

__device__ __forceinline__ float sgm(float x) { return 1.f / (1.f + __expf(-x)); }
__device__ __forceinline__ float tnh(float x) { return 1.f - 2.f / (__expf(2.f * x) + 1.f); }

// item pids (21 + wrap): F1,H1,Q1 | F1,F2,F4,H1,H4,H2,Q3,Q1 | F1,F2,F4,H1,H4,H2
// | A,B,SR,SK | F1.  pid map: 0:F1 1:F2 2:F4 3:H1 4:H2 5:H4 6:Q1 7:Q3 8:A 9:B
// 10:SR 11:SK
__device__ __forceinline__ int pid_of(int idx) {
  const unsigned long long P0 = 0x5321067453210630ull;   // idx 0..15
  const unsigned long long P1 = 0x00000000000BA984ull;   // idx 16..21
  const unsigned long long v = (idx < 16) ? (P0 >> (idx * 4))
                                          : (P1 >> ((idx - 16) * 4));
  return (int)(v & 15);
}

// desc: tail(0..7) | p<<3 | att<<5 | asel<<6 | reset<<7 ; entry = xoff|desc<<16
#define DE(x, d) ((u32)(x) | ((u32)(d) << 16))
__device__ const u32 ITBL[21] = {
  DE(OFF_XQR,       0x80),   //  0 F1@xqr    reset a0
  DE(OFF_XQR,       0xC1),   //  1 H1@xqr    reset a1, tail FH0
  DE(OFF_H2,        0xA4),   //  2 Q1@h1     reset a0, att, tail Q p0
  DE(OFF_XQR,       0x80),   //  3 F1@xqr    reset a0           (it1)
  DE(OFF_H2,        0x00),   //  4 F2@h1
  DE(OFF_Q2,        0x00),   //  5 F4@q1
  DE(OFF_XQR,       0xC0),   //  6 H1@xqr    reset a1
  DE(OFF_Q2,        0x42),   //  7 H4@q1     a1, tail F p0
  DE(OFF_XFH,       0x40),   //  8 H2@fh     a1
  DE(OFF_Q2,        0x8B),   //  9 Q3@q1     reset a0, tail H p1 (h2->slot1)
  DE(OFF_H2 + 128,  0x2C),   // 10 Q1@h2     a0, att, tail Q p1  (q2->slot1)
  DE(OFF_XQR,       0x80),   // 11 F1@xqr    reset a0           (it2)
  DE(OFF_H2 + 128,  0x00),   // 12 F2@h2
  DE(OFF_Q2 + 128,  0x00),   // 13 F4@q2
  DE(OFF_XQR,       0xC0),   // 14 H1@xqr    reset a1
  DE(OFF_Q2 + 128,  0x4A),   // 15 H4@q2     a1, tail F p1
  DE(OFF_XFH,       0x43),   // 16 H2@fh     a1, tail H p0 (h3->slot0)
  DE(OFF_H2,        0x80),   // 17 A@h3      reset a0
  DE(OFF_Q2 + 128,  0x05),   // 18 B@q2      a0, tail O
  DE(OFF_XO,        0x86),   // 19 SR@xo     reset, tail SR
  DE(OFF_XO,        0x87)};  // 20 SK@xo     reset, tail SK

// load one K-quarter slice (8x16B = 64 f16 = 32 VGPRs) for this thread
#define ISSQ(BUF, P, C) {                                                     \
    const u32* gp_ = pan_lane + (((P) << 15) + ((C) << 11));                  \
    _Pragma("unroll")                                                         \
    for (int r_ = 0; r_ < 8; ++r_) BUF[r_] = *(const u32x4*)(gp_ + (r_ << 8)); \
    SB(); }

// one quarter: 32 fdot2 (64 MACs); xq = packed x for this quarter (32 u32)
__device__ __forceinline__ float cq(const u32x4 (&buf)[8], const u32* xq) {
  float a = 0.f;
#pragma unroll
  for (int r = 0; r < 8; ++r) {
    const u32x4 wv = buf[r];
    const u32x4 xv = *(const u32x4*)(xq + (r << 2));
    FDOT2(a, wv[0], xv[0]); FDOT2(a, wv[1], xv[1]);
    FDOT2(a, wv[2], xv[2]); FDOT2(a, wv[3], xv[3]);
  }
  return a;
}

__device__ __forceinline__ void qres_phase(u32* lds, int w8, int col) {
  float qr = 0.f;
  const u32* sp = lds + OFF_SREPT + col * 37;
  const u32* ap = lds + OFF_ATTW + (w8 << 5);
#pragma unroll
  for (int nq = 0; nq < 8; ++nq) {
    const u32x4 sv = *(const u32x4*)(sp + (nq << 2));
    const u32x4 av = *(const u32x4*)(ap + (nq << 2));
    FDOT2(qr, sv[0], av[0]); FDOT2(qr, sv[1], av[1]);
    FDOT2(qr, sv[2], av[2]); FDOT2(qr, sv[3], av[3]);
  }
  ((u16*)(lds + OFF_XQR))[col] = f16b(qr);
}

__device__ __forceinline__ void logits_phase(u32* lds, int w8, int l,
                                             float mk, int cp) {
  float la = 0.f;
  const u32* kp = lds + OFF_SKEY + l * 133;
  const u32* qp = lds + OFF_Q2 + cp * 128;
#pragma unroll
  for (int kq = 0; kq < 32; ++kq) {
    const u32x4 kv = *(const u32x4*)(kp + (kq << 2));
    const u32x4 qv = *(const u32x4*)(qp + (kq << 2));
    FDOT2(la, kv[0], qv[0]); FDOT2(la, kv[1], qv[1]);
    FDOT2(la, kv[2], qv[2]); FDOT2(la, kv[3], qv[3]);
  }
  float mx = la;
#pragma unroll
  for (int o = 1; o < 64; o <<= 1) mx = fmaxf(mx, __shfl_xor(mx, o, 64));
  const float e = __expf(la - mx) * mk;
  float sm = e;
#pragma unroll
  for (int o = 1; o < 64; o <<= 1) sm += __shfl_xor(sm, o, 64);
  ((u16*)(lds + OFF_ATTW))[(w8 << 6) + l] = f16b(e / sm);
}

__global__ __launch_bounds__(512) void dagsage_main(
    const float* __restrict__ adj,
    const float* __restrict__ b_srep, const float* __restrict__ b_skey,
    const float* __restrict__ pf, const float* __restrict__ ph,
    const float* __restrict__ pq, const float* __restrict__ poO,
    const u16* __restrict__ panels,
    float* __restrict__ outp) {
  __shared__ u32 lds[LDS_U32];
  const int t = threadIdx.x;
  const int w8 = t >> 6, l = t & 63;
  const int g = l >> 5;                 // in-wave K-half
  const int col = (w8 << 5) + (l & 31);
  const int xq0 = g << 6;               // u32 offset of my half's 2 quarters
  const int b = blockIdx.x;

  // ---- init srepT / skey (out_nodes==0 -> rows are biases) ----
  {
    const float bs0 = b_srep[col];
    for (int j = g * 16; j < g * 16 + 16; ++j)
      lds[OFF_SREPT + col * 37 + j] = pk2f(bs0, bs0);
    const int n = t >> 3, kk0 = (t & 7) * 16;
    for (int j = 0; j < 16; ++j) {
      const int kk = kk0 + j;
      lds[OFF_SKEY + n * 133 + kk] =
          pk2f(b_skey[2 * kk], b_skey[2 * kk + 1]);
    }
  }
  __syncthreads();

  const float bsv = b_srep[col];
  const float bkv = b_skey[col];
  const u32* pan_lane = (const u32*)panels + (w8 << 12) + (l << 2);

  u32x4 bufA[8], bufB[8], bufC[8];
  ISSQ(bufA, PID_F1, 0);   // prologue: F1 q0
  ISSQ(bufB, PID_F1, 1);   // prologue: F1 q1

// One item with 3-buffer rotation: B0 holds q0(cur), B1 holds q1(cur),
// B2 is free. Issues BOTH quarters of item IT+1 (into B2 and B0).
#define ITEM(B0, B1, B2, IT) {                                                \
    const u32 cur = ITBL[IT];                                                 \
    const u32 d = cur >> 16;                                                  \
    const u32* xq = lds + (cur & 0xFFFF) + xq0;                               \
    const int pn = pid_of((IT) + 1);                                          \
    ISSQ(B2, pn, 0);                                                          \
    float acc = cq(B0, xq); SB();                                             \
    ISSQ(B0, pn, 1);                                                          \
    acc += cq(B1, xq + 32); SB();                                             \
    if (d & 0x80) { if (d & 0x40) a1 = acc;  else a0 = acc; }                 \
    else          { if (d & 0x40) a1 += acc; else a0 += acc; }                 \
    const int tl = d & 7;                                                     \
    if (tl) {                                                                 \
      const int p = (d >> 3) & 1;                                             \
      const float A0 = a0 + __shfl_xor(a0, 32, 64);                           \
      const float A1 = a1 + __shfl_xor(a1, 32, 64);                           \
      switch (tl) {                                                           \
        case 1: {  /* FH0 */                                                  \
          frv = sgm(A0 + pfv);                                                \
          ((u16*)(lds + OFF_H2))[col] = f16b((1.f - frv) * tnh(A1 + phv));    \
        } break;                                                              \
        case 2: {  /* F */                                                    \
          frv = sgm(A0 + pfv);                                                \
          fhv = frv * f16f(((const u16*)(lds + OFF_H2))[p * 256 + col]);      \
          ((u16*)(lds + OFF_XFH))[col] = f16b(fhv);                           \
        } break;                                                              \
        case 3: {  /* H */                                                    \
          ((u16*)(lds + OFF_H2))[p * 256 + col] =                             \
              f16b(fhv + (1.f - frv) * tnh(A1 + phv));                        \
        } break;                                                              \
        case 4: {  /* Q */                                                    \
          ((u16*)(lds + OFF_Q2))[p * 256 + col] = f16b(A0 + pqv);             \
        } break;                                                              \
        case 5: {  /* O: out = h3@A + q2@B + poO */                           \
          const float ov = A0 + pov;                                          \
          if (l < 32) outp[ro] = ov;                                          \
          ((u16*)(lds + OFF_XO))[col] = f16b(ov);                             \
        } break;                                                              \
        case 6: {  /* SR: srep row i (own col; same-thread dep only) */       \
          ((u16*)(lds + OFF_SREPT))[col * 74 + i] = f16b(A0 + bsv);           \
        } break;                                                              \
        case 7: {  /* SK: skey row i (consumed after later barriers) */       \
          ((u16*)(lds + OFF_SKEY))[i * 266 + col] = f16b(A0 + bkv);           \
        } break;                                                              \
        default: break;                                                       \
      }                                                                       \
      if (tl < 6) BAR();                                                      \
      if ((tl == 4) && (d & 0x20)) {   /* attention for next iteration */     \
        logits_phase(lds, w8, l, mk, p);                                      \
        qres_phase(lds, w8, col);                                             \
        BAR();                                                                \
      }                                                                       \
    }                                                                         \
  }

#pragma unroll 1
  for (int i = 0; i < 64; ++i) {
    const int ro = (b * 64 + i) * 256 + col;
    const float pfv = pf[ro], phv = ph[ro], pqv = pq[ro], pov = poO[ro];
    const float mk = adj[(b * 64 + l) * 64 + i];

    // it0 attention weights (per-wave copy): attw = mk / sum(mk)
    {
      float sm = mk;
#pragma unroll
      for (int o = 1; o < 64; o <<= 1) sm += __shfl_xor(sm, o, 64);
      ((u16*)(lds + OFF_ATTW))[(w8 << 6) + l] = f16b(mk / sm);
    }
    qres_phase(lds, w8, col);
    BAR();

    float a0 = 0.f, a1 = 0.f, frv = 0.f, fhv = 0.f;

#pragma unroll 1
    for (int itg = 0; itg < 21; itg += 3) {
      ITEM(bufA, bufB, bufC, itg);
      ITEM(bufC, bufA, bufB, itg + 1);
      ITEM(bufB, bufC, bufA, itg + 2);
    }
    // after 21 items (21 % 3 == 0): bufA = q0(F1 next step), bufB = q1.
  }
}

// ---------------------------------------------------------------------------
extern "C" void kernel_launch(void* const* d_in, const int* in_sizes, int n_in,
                              void* d_out, int out_size, void* d_ws, size_t ws_size,
                              hipStream_t stream) {
  const float* nodes    = (const float*)d_in[0];
  const float* adj      = (const float*)d_in[1];
  const float* W_self   = (const float*)d_in[2];
  const float* b_self   = (const float*)d_in[3];
  const float* W_srep   = (const float*)d_in[4];
  const float* b_srep   = (const float*)d_in[5];
  const float* W_skey   = (const float*)d_in[6];
  const float* b_skey   = (const float*)d_in[7];
  const float* W_forget = (const float*)d_in[8];
  const float* b_forget = (const float*)d_in[9];
  const float* W_hid    = (const float*)d_in[10];
  const float* b_hid    = (const float*)d_in[11];
  const float* W_query  = (const float*)d_in[12];
  const float* b_query  = (const float*)d_in[13];
  const float* W_out    = (const float*)d_in[14];
  const float* b_out    = (const float*)d_in[15];
  float* out = (float*)d_out;

  float* rep = (float*)d_ws;           // 524288
  float* pf  = rep + 524288;
  float* ph  = pf + 524288;
  float* pq  = ph + 524288;
  float* po  = pq + 524288;            // becomes poO in-place
  u16* panels = (u16*)(po + 524288);   // 12 * 65536 u16
  // temporaries in the pf region BEFORE g2 runs (cvt consumes them first)
  float* tmpA = pf;                    // 65536
  float* tmpB = pf + 65536;

  const float* Q1 = W_query;               // rows 0:256
  const float* O3 = W_out + 512 * 256;

  hipMemcpyAsync(out + 524288, adj, 131072 * sizeof(float),
                 hipMemcpyDeviceToDevice, stream);

  // 1) out-fold precomputes (f32, exact)
  gemmD<<<16, 256, 0, stream>>>(Q1, O3, W_out, tmpA);                // A = Q1@O3 + O1
  gemmD<<<16, 256, 0, stream>>>(W_query + 512 * 256, O3, nullptr, tmpB); // B = Q3@O3

  // 2) convert 12 panels (consumes tmpA/tmpB; stream-ordered before g2)
  C12 ca;
  ca.src[0]  = W_forget;             // F1  (rows 0:256   <- query_res)
  ca.src[1]  = W_forget + 256 * 256; // F2  (rows 256:512 <- hidden)
  ca.src[2]  = W_forget + 768 * 256; // F4  (rows 768:1024<- query)
  ca.src[3]  = W_hid;                // H1
  ca.src[4]  = W_hid + 256 * 256;    // H2  (<- forget*hidden)
  ca.src[5]  = W_hid + 768 * 256;    // H4
  ca.src[6]  = W_query;              // Q1  (rows 0:256 <- hidden)
  ca.src[7]  = W_query + 512 * 256;  // Q3  (rows 512:768 <- query)
  ca.src[8]  = tmpA;                 // A   (replaces O1)
  ca.src[9]  = tmpB;                 // B   (replaces O3)
  ca.src[10] = W_srep;               // SR
  ca.src[11] = W_skey;               // SK
  cvt_panels<<<dim3(256, 12), 256, 0, stream>>>(ca, panels);

  // 3) per-(b,i) precomputes (overwrite tmp area safely now)
  G4 g1;
  for (int j = 0; j < 4; ++j) { g1.Bm[j] = W_self; g1.bias[j] = b_self; g1.C[j] = rep; }
  gemm16<<<dim3(128, 1), 256, 0, stream>>>(nodes, g1);

  G4 g2;
  g2.Bm[0] = W_forget + 512 * 256; g2.bias[0] = b_forget; g2.C[0] = pf;
  g2.Bm[1] = W_hid + 512 * 256;    g2.bias[1] = b_hid;    g2.C[1] = ph;
  g2.Bm[2] = W_query + 256 * 256;  g2.bias[2] = b_query;  g2.C[2] = pq;
  g2.Bm[3] = W_out + 256 * 256;    g2.bias[3] = b_out;    g2.C[3] = po;
  gemm16<<<dim3(128, 4), 256, 0, stream>>>(rep, g2);

  gemmD<<<128, 256, 0, stream>>>(pq, O3, po, po);    // poO = pq@O3 + po

  dagsage_main<<<32, 512, 0, stream>>>(adj, b_srep, b_skey,
                                       pf, ph, pq, po, panels, out);
}